// Round 5
// baseline (310.519 us; speedup 1.0000x reference)
//
#include <hip/hip_runtime.h>
#include <hip/hip_bf16.h>

// Problem constants: B,T,V,E,U = 256,512,20000,128,128
#define BB 256
#define TT 512
#define VV 20000
#define EE 128
#define UU 128
#define G4 512   // 4*U gate width

typedef _Float16 f16x8 __attribute__((ext_vector_type(8)));
typedef float    f32x4 __attribute__((ext_vector_type(4)));

// Fast device math: error ~1e-6, vastly under the 1e-2 absmax threshold.
__device__ __forceinline__ float sigmoid_f(float x) {
    float e = __expf(-x);
    return __builtin_amdgcn_rcpf(1.0f + e);
}
__device__ __forceinline__ float tanh_f(float x) {
    float e = __expf(2.0f * x);
    return 1.0f - 2.0f * __builtin_amdgcn_rcpf(e + 1.0f);
}

// ---------------------------------------------------------------------------
// Phase 1: projected-token table  P[v][g] = sum_e emb[v][e]*K[e][g] + bias[g]
// ---------------------------------------------------------------------------
__global__ __launch_bounds__(512, 2) void proj_kernel(
    const float* __restrict__ emb, const float* __restrict__ wk,
    const float* __restrict__ bias, float* __restrict__ P) {
    const int col = threadIdx.x;
    const int v0  = blockIdx.x * 16;

    __shared__ float elds[16 * EE];
    ((float4*)elds)[col] = ((const float4*)(emb + (size_t)v0 * EE))[col];
    __syncthreads();

    float bcol = bias[col];
    float acc[16];
#pragma unroll
    for (int r = 0; r < 16; ++r) acc[r] = bcol;

    const float4* elds4 = (const float4*)elds;
    for (int e0 = 0; e0 < EE; e0 += 4) {
        float k0 = wk[(e0 + 0) * G4 + col];
        float k1 = wk[(e0 + 1) * G4 + col];
        float k2 = wk[(e0 + 2) * G4 + col];
        float k3 = wk[(e0 + 3) * G4 + col];
#pragma unroll
        for (int r = 0; r < 16; ++r) {
            float4 ev = elds4[r * 32 + (e0 >> 2)];
            acc[r] = fmaf(ev.x, k0, acc[r]);
            acc[r] = fmaf(ev.y, k1, acc[r]);
            acc[r] = fmaf(ev.z, k2, acc[r]);
            acc[r] = fmaf(ev.w, k3, acc[r]);
        }
    }
#pragma unroll
    for (int r = 0; r < 16; ++r)
        P[(size_t)(v0 + r) * G4 + col] = acc[r];
}

// ---------------------------------------------------------------------------
// Phase 2: sequential LSTM via MFMA (round-4 structure) with:
//  * raw s_barrier + lgkmcnt(0)-only drain -> global P prefetch stays in
//    flight ACROSS the per-step barrier (T4 counted-vmcnt pattern); depth-2
//    prefetch pipeline gives ~2 iterations of latency slack.
//  * gate-specialized activations: lane 16g+j activates only gate g of
//    unit j (2 trans ops instead of 10); i,f,g,o gathered to kq==0 lanes
//    via 3 intra-wave shuffles for the c/h update.
//  * first MFMA consumes a hoisted zero C (no 16 acc-init movs); P is added
//    after the MFMAs so its vmcnt wait lands mid-step, not at the top.
// ---------------------------------------------------------------------------
__global__ __launch_bounds__(512, 2) void lstm_kernel(
    const int* __restrict__ tokens, const float* __restrict__ rk,
    const float* __restrict__ P, const float* __restrict__ dense_w,
    const float* __restrict__ dense_b, float* __restrict__ out) {
    const int tid = threadIdx.x;
    const int w   = tid >> 6;       // wave 0..7
    const int l   = tid & 63;       // lane
    const int j   = l & 15;         // unit index within the wave's 16
    const int kq  = l >> 4;         // lane's gate (0=i,1=f,2=g,3=o)
    const int b   = blockIdx.x;
    const int ucol = 16 * w + j;    // unit column

    __shared__ __align__(16) _Float16 hbuf[2][UU];  // double-buffered h
    __shared__ float red[8];

    // ---- B-fragments: bf[kt][g][i] = rk[32kt+8kq+i][g*128 + ucol] (f16) ----
    f16x8 bf[4][4];
#pragma unroll
    for (int kt = 0; kt < 4; ++kt) {
#pragma unroll
        for (int g = 0; g < 4; ++g) {
            f16x8 v;
#pragma unroll
            for (int i = 0; i < 8; ++i) {
                v[i] = (_Float16)rk[(size_t)(32 * kt + 8 * kq + i) * G4
                                    + g * 128 + ucol];
            }
            bf[kt][g] = v;
        }
    }

    if (tid < UU) hbuf[0][tid] = (_Float16)0.f;   // h0 = 0
    float c_state = 0.f, hv = 0.f;

    const int* trow = tokens + (size_t)b * TT;
    const float* Pcol = P + (size_t)kq * 128 + ucol;  // this lane's P column
    float pc = Pcol[(size_t)trow[0] * G4];   // P for t
    float pn = Pcol[(size_t)trow[1] * G4];   // P for t+1
    __syncthreads();

    const f32x4 cz = {0.f, 0.f, 0.f, 0.f};

    for (int t = 0; t < TT; ++t) {
        // --- issue P prefetch for t+2 (stays in flight across the barrier) ---
        int tok2 = trow[(t + 2 < TT) ? (t + 2) : (TT - 1)];
        float p2 = Pcol[(size_t)tok2 * G4];

        // --- A-fragments: h broadcast slices from LDS ---
        f16x8 af[4];
#pragma unroll
        for (int kt = 0; kt < 4; ++kt)
            af[kt] = *(const f16x8*)&hbuf[t & 1][32 * kt + 8 * kq];

        // --- z = h @ R : 4 independent chains, 16 MFMA, zero-C first ---
        f32x4 acc[4];
#pragma unroll
        for (int g = 0; g < 4; ++g)
            acc[g] = __builtin_amdgcn_mfma_f32_16x16x32_f16(af[0], bf[0][g], cz, 0, 0, 0);
#pragma unroll
        for (int kt = 1; kt < 4; ++kt) {
#pragma unroll
            for (int g = 0; g < 4; ++g)
                acc[g] = __builtin_amdgcn_mfma_f32_16x16x32_f16(af[kt], bf[kt][g], acc[g], 0, 0, 0);
        }

        // --- this lane's gate value: z[kq][unit j] (+ its P, waited here) ---
        float z0 = acc[0][0], z1 = acc[1][0], z2 = acc[2][0], z3 = acc[3][0];
        float zl = (kq & 2) ? ((kq & 1) ? z3 : z2) : ((kq & 1) ? z1 : z0);
        zl += pc;

        // --- one activation per lane (tanh via sigmoid identity for kq==2) ---
        float xs = (kq == 2) ? zl + zl : zl;
        float s  = sigmoid_f(xs);
        float a  = (kq == 2) ? fmaf(2.f, s, -1.f) : s;

        // --- gather i,f,g,o of unit j to the kq==0 lanes ---
        float fa = __shfl(a, j + 16, 64);
        float ga = __shfl(a, j + 32, 64);
        float oa = __shfl(a, j + 48, 64);

        // --- state update (valid on kq==0 lanes; garbage elsewhere unused) ---
        c_state = fmaf(fa, c_state, a * ga);
        hv      = oa * tanh_f(c_state);

        if (kq == 0) hbuf[(t + 1) & 1][ucol] = (_Float16)hv;  // publish h
        pc = pn; pn = p2;

        // LDS-only drain + raw barrier: P loads survive into next step
        asm volatile("s_waitcnt lgkmcnt(0)" ::: "memory");
        __builtin_amdgcn_s_barrier();
    }

    // --- dense sigmoid head: out[b] = sigmoid(h @ w + b) ---
    float val = (kq == 0) ? hv * dense_w[ucol] : 0.f;
#pragma unroll
    for (int off = 32; off > 0; off >>= 1) val += __shfl_xor(val, off, 64);
    if (l == 0) red[w] = val;
    __syncthreads();
    if (tid == 0) {
        float sum = dense_b[0];
#pragma unroll
        for (int i = 0; i < 8; ++i) sum += red[i];
        out[b] = sigmoid_f(sum);
    }
}

extern "C" void kernel_launch(void* const* d_in, const int* in_sizes, int n_in,
                              void* d_out, int out_size, void* d_ws, size_t ws_size,
                              hipStream_t stream) {
    const int*   tokens = (const int*)  d_in[0];
    const float* emb    = (const float*)d_in[1];
    const float* wk     = (const float*)d_in[2];
    const float* rk     = (const float*)d_in[3];
    const float* bias   = (const float*)d_in[4];
    const float* dw     = (const float*)d_in[5];
    const float* db     = (const float*)d_in[6];
    float* out = (float*)d_out;
    float* P   = (float*)d_ws;     // 20000*512*4 = 40.96 MB scratch

    proj_kernel<<<VV / 16, 512, 0, stream>>>(emb, wk, bias, P);
    lstm_kernel<<<BB, 512, 0, stream>>>(tokens, rk, P, dw, db, out);
}

// Round 6
// 289.544 us; speedup vs baseline: 1.0724x; 1.0724x over previous
//
#include <hip/hip_runtime.h>
#include <hip/hip_bf16.h>

// Problem constants: B,T,V,E,U = 256,512,20000,128,128
#define BB 256
#define TT 512
#define VV 20000
#define EE 128
#define UU 128
#define G4 512   // 4*U gate width

typedef _Float16 f16x8 __attribute__((ext_vector_type(8)));
typedef float    f32x4 __attribute__((ext_vector_type(4)));

// Fast device math: error ~1e-6, vastly under the 1e-2 absmax threshold.
__device__ __forceinline__ float sigmoid_f(float x) {
    float e = __expf(-x);
    return __builtin_amdgcn_rcpf(1.0f + e);
}
__device__ __forceinline__ float tanh_f(float x) {
    float e = __expf(2.0f * x);
    return 1.0f - 2.0f * __builtin_amdgcn_rcpf(e + 1.0f);
}

// ---------------------------------------------------------------------------
// Phase 1: projected-token table  P[v][g] = sum_e emb[v][e]*K[e][g] + bias[g]
// ---------------------------------------------------------------------------
__global__ __launch_bounds__(512, 2) void proj_kernel(
    const float* __restrict__ emb, const float* __restrict__ wk,
    const float* __restrict__ bias, float* __restrict__ P) {
    const int col = threadIdx.x;
    const int v0  = blockIdx.x * 16;

    __shared__ float elds[16 * EE];
    ((float4*)elds)[col] = ((const float4*)(emb + (size_t)v0 * EE))[col];
    __syncthreads();

    float bcol = bias[col];
    float acc[16];
#pragma unroll
    for (int r = 0; r < 16; ++r) acc[r] = bcol;

    const float4* elds4 = (const float4*)elds;
    for (int e0 = 0; e0 < EE; e0 += 4) {
        float k0 = wk[(e0 + 0) * G4 + col];
        float k1 = wk[(e0 + 1) * G4 + col];
        float k2 = wk[(e0 + 2) * G4 + col];
        float k3 = wk[(e0 + 3) * G4 + col];
#pragma unroll
        for (int r = 0; r < 16; ++r) {
            float4 ev = elds4[r * 32 + (e0 >> 2)];
            acc[r] = fmaf(ev.x, k0, acc[r]);
            acc[r] = fmaf(ev.y, k1, acc[r]);
            acc[r] = fmaf(ev.z, k2, acc[r]);
            acc[r] = fmaf(ev.w, k3, acc[r]);
        }
    }
#pragma unroll
    for (int r = 0; r < 16; ++r)
        P[(size_t)(v0 + r) * G4 + col] = acc[r];
}

// ---------------------------------------------------------------------------
// Phase 2: sequential LSTM via MFMA with a REAL depth-4 P prefetch:
//  * t-loop unrolled x4, pf[0..3] statically indexed -> loop-carried SSA,
//    no rotation copies -> no forced vmcnt(0) per step (round 5's stall).
//    Load issued at step t is consumed at t+4 (~2000 cy slack >> L3 latency);
//    compiler emits a counted vmcnt instead of a drain.
//  * tokens staged once into LDS (2 KB); token[t+4] read at step top via
//    ds_read_b32 so the P-load address is ready long before issue.
//  * raw s_barrier + lgkmcnt(0)-only drain (global loads cross the barrier).
//  * gate-specialized activations, 3 shuffles to the kq==0 lanes (round 5).
// ---------------------------------------------------------------------------
__global__ __launch_bounds__(512, 2) void lstm_kernel(
    const int* __restrict__ tokens, const float* __restrict__ rk,
    const float* __restrict__ P, const float* __restrict__ dense_w,
    const float* __restrict__ dense_b, float* __restrict__ out) {
    const int tid = threadIdx.x;
    const int w   = tid >> 6;       // wave 0..7
    const int l   = tid & 63;       // lane
    const int j   = l & 15;         // unit index within the wave's 16
    const int kq  = l >> 4;         // lane's gate (0=i,1=f,2=g,3=o)
    const int b   = blockIdx.x;
    const int ucol = 16 * w + j;    // unit column

    __shared__ __align__(16) _Float16 hbuf[2][UU];  // double-buffered h
    __shared__ int   tokLDS[TT];                    // whole token row (2 KB)
    __shared__ float red[8];

    // ---- B-fragments: bf[kt][g][i] = rk[32kt+8kq+i][g*128 + ucol] (f16) ----
    f16x8 bf[4][4];
#pragma unroll
    for (int kt = 0; kt < 4; ++kt) {
#pragma unroll
        for (int g = 0; g < 4; ++g) {
            f16x8 v;
#pragma unroll
            for (int i = 0; i < 8; ++i) {
                v[i] = (_Float16)rk[(size_t)(32 * kt + 8 * kq + i) * G4
                                    + g * 128 + ucol];
            }
            bf[kt][g] = v;
        }
    }

    const int* trow = tokens + (size_t)b * TT;
    tokLDS[tid] = trow[tid];                 // 512 threads = 512 tokens
    if (tid < UU) hbuf[0][tid] = (_Float16)0.f;   // h0 = 0
    float c_state = 0.f, hv = 0.f;

    const float* Pcol = P + (size_t)kq * 128 + ucol;  // this lane's P column
    // depth-4 prologue: P for t = 0..3
    float pf[4];
#pragma unroll
    for (int s = 0; s < 4; ++s) pf[s] = Pcol[(size_t)trow[s] * G4];
    __syncthreads();

    const f32x4 cz = {0.f, 0.f, 0.f, 0.f};

    for (int t = 0; t < TT; t += 4) {
#pragma unroll
        for (int s = 0; s < 4; ++s) {
            // --- token for t+s+4 (LDS, hot) — address ready early ---
            int tki  = t + s + 4; if (tki > TT - 1) tki = TT - 1;
            int vtok = tokLDS[tki];

            // --- A-fragments: h broadcast slices from LDS ---
            f16x8 af[4];
#pragma unroll
            for (int kt = 0; kt < 4; ++kt)
                af[kt] = *(const f16x8*)&hbuf[s & 1][32 * kt + 8 * kq];

            // --- z = h @ R : 4 independent chains, 16 MFMA, zero-C first ---
            f32x4 acc[4];
#pragma unroll
            for (int g = 0; g < 4; ++g)
                acc[g] = __builtin_amdgcn_mfma_f32_16x16x32_f16(af[0], bf[0][g], cz, 0, 0, 0);
#pragma unroll
            for (int kt = 1; kt < 4; ++kt) {
#pragma unroll
                for (int g = 0; g < 4; ++g)
                    acc[g] = __builtin_amdgcn_mfma_f32_16x16x32_f16(af[kt], bf[kt][g], acc[g], 0, 0, 0);
            }

            // --- this lane's gate value: z[kq][unit j] + P (counted vmcnt) ---
            float z0 = acc[0][0], z1 = acc[1][0], z2 = acc[2][0], z3 = acc[3][0];
            float zl = (kq & 2) ? ((kq & 1) ? z3 : z2) : ((kq & 1) ? z1 : z0);
            zl += pf[s];

            // --- one activation per lane (tanh via sigmoid identity, kq==2) ---
            float xs = (kq == 2) ? zl + zl : zl;
            float sg = sigmoid_f(xs);
            float a  = (kq == 2) ? fmaf(2.f, sg, -1.f) : sg;

            // --- gather i,f,g,o of unit j to the kq==0 lanes ---
            float fa = __shfl(a, j + 16, 64);
            float ga = __shfl(a, j + 32, 64);
            float oa = __shfl(a, j + 48, 64);

            // --- state update (valid on kq==0 lanes) ---
            c_state = fmaf(fa, c_state, a * ga);
            hv      = oa * tanh_f(c_state);

            if (kq == 0) hbuf[(s + 1) & 1][ucol] = (_Float16)hv;  // publish h

            // --- issue P prefetch for t+s+4 (in flight for ~4 steps) ---
            pf[s] = Pcol[(size_t)vtok * G4];

            // LDS-only drain + raw barrier: P loads survive across steps
            asm volatile("s_waitcnt lgkmcnt(0)" ::: "memory");
            __builtin_amdgcn_s_barrier();
        }
    }

    // --- dense sigmoid head: out[b] = sigmoid(h @ w + b) ---
    float val = (kq == 0) ? hv * dense_w[ucol] : 0.f;
#pragma unroll
    for (int off = 32; off > 0; off >>= 1) val += __shfl_xor(val, off, 64);
    if (l == 0) red[w] = val;
    __syncthreads();
    if (tid == 0) {
        float sum = dense_b[0];
#pragma unroll
        for (int i = 0; i < 8; ++i) sum += red[i];
        out[b] = sigmoid_f(sum);
    }
}

extern "C" void kernel_launch(void* const* d_in, const int* in_sizes, int n_in,
                              void* d_out, int out_size, void* d_ws, size_t ws_size,
                              hipStream_t stream) {
    const int*   tokens = (const int*)  d_in[0];
    const float* emb    = (const float*)d_in[1];
    const float* wk     = (const float*)d_in[2];
    const float* rk     = (const float*)d_in[3];
    const float* bias   = (const float*)d_in[4];
    const float* dw     = (const float*)d_in[5];
    const float* db     = (const float*)d_in[6];
    float* out = (float*)d_out;
    float* P   = (float*)d_ws;     // 20000*512*4 = 40.96 MB scratch

    proj_kernel<<<VV / 16, 512, 0, stream>>>(emb, wk, bias, P);
    lstm_kernel<<<BB, 512, 0, stream>>>(tokens, rk, P, dw, db, out);
}